// Round 1
// 136.635 us; speedup vs baseline: 1.0028x; 1.0028x over previous
//
#include <hip/hip_runtime.h>
#include <hip/hip_bf16.h>
#include <math.h>

#define S_LEN 8192
#define DK    128
#define BM    64
#define BN    64
#define NQT   (S_LEN / BM)     // 128 query tiles
// (1/sqrt(128)) * log2(e): softmax tracked in base-2 domain
#define SCALE2 (0.08838834764831845f * 1.4426950408889634f)

typedef __bf16 bf16x8_t __attribute__((ext_vector_type(8)));
typedef __bf16 bf16x4_t __attribute__((ext_vector_type(4)));
typedef float  floatx4  __attribute__((ext_vector_type(4)));

// async global->LDS, 16 B per lane; LDS dst is wave-uniform base + lane*16
#define GLD16(g, l) __builtin_amdgcn_global_load_lds(                      \
    (const __attribute__((address_space(1))) void*)(g),                    \
    (__attribute__((address_space(3))) void*)(l), 16, 0, 0)

__device__ __forceinline__ float fexp2(float x) {
#if __has_builtin(__builtin_amdgcn_exp2f)
  return __builtin_amdgcn_exp2f(x);
#else
  return exp2f(x);
#endif
}

// ---- fused prep: K fp32->bf16 row-major; V fp32->bf16 transposed Vt[d][s] ----
__global__ __launch_bounds__(256) void prep_kv(const float* __restrict__ K,
                                               const float* __restrict__ V,
                                               __bf16* __restrict__ Kb,
                                               __bf16* __restrict__ Vt) {
  __shared__ __bf16 t[64][DK + 8];
  const int bx  = blockIdx.x;
  const int tid = threadIdx.x;
  if (bx < (S_LEN * DK) / (256 * 4)) {            // K conversion part
    const int i = (bx * 256 + tid) * 4;
    float4 v = *(const float4*)&K[i];
    bf16x4_t b;
    b[0] = (__bf16)v.x; b[1] = (__bf16)v.y; b[2] = (__bf16)v.z; b[3] = (__bf16)v.w;
    *(bf16x4_t*)&Kb[i] = b;
    return;
  }
  // V transpose part
  const int key0 = (bx - (S_LEN * DK) / (256 * 4)) * 64;
  {
    const int r = tid >> 2, cg = (tid & 3) * 32;
    const float* vp = V + (size_t)(key0 + r) * DK + cg;
    #pragma unroll
    for (int i = 0; i < 8; ++i) {
      float4 v = ((const float4*)vp)[i];
      bf16x4_t b;
      b[0] = (__bf16)v.x; b[1] = (__bf16)v.y; b[2] = (__bf16)v.z; b[3] = (__bf16)v.w;
      *(bf16x4_t*)&t[r][cg + i * 4] = b;
    }
  }
  __syncthreads();
  const int d = tid >> 1, h = (tid & 1) * 32;
  __bf16* op = Vt + (size_t)d * S_LEN + key0 + h;
  #pragma unroll
  for (int jb = 0; jb < 4; ++jb) {
    bf16x8_t b;
    #pragma unroll
    for (int j = 0; j < 8; ++j) b[j] = t[h + jb * 8 + j][d];
    *(bf16x8_t*)&op[jb * 8] = b;
  }
}

// ---- flash attention partial, fixed-size-C key chunks, compact chunk index ----
// Ks: 64 key-rows x 128 d (double-buffered), XOR-swizzled: phys = c ^ (row&15)
// Vts: 128 d-rows x 64 keys, swizzled: phys = c ^ (row&7)
__global__ __launch_bounds__(256, 2)
void fa_part(const float* __restrict__ Q, const __bf16* __restrict__ Kb,
             const __bf16* __restrict__ Vtg, float* __restrict__ Opart,
             float* __restrict__ stats, int C, int direct) {
  __shared__ __align__(16) __bf16 Ks[2][BN * DK];        // 32 KB (dbuf)
  __shared__ __align__(16) __bf16 Vts[BN * DK];          // 16 KB
  __shared__ __align__(16) __bf16 Pl[4][16][BN + 8];     // 9.2 KB (wave-private)

  const int tid  = threadIdx.x;
  const int wave = tid >> 6;
  const int lane = tid & 63;
  const int l15  = lane & 15;
  const int quad = lane >> 4;

  const int qtile = (NQT - 1) - blockIdx.x;   // longest chunks dispatch first
  const int g     = blockIdx.y;
  const int nt    = qtile + 1;
  const int ca    = qtile / C;                // chunks for this qtile = ca+1
  if (g > ca) return;
  const int cr  = qtile - ca * C;
  const int jb0 = g * C;
  const int jb1 = (jb0 + C < nt) ? (jb0 + C) : nt;
  // flat chunk index: sum_{q'<qtile}(floor(q'/C)+1) + g
  const int chunk = qtile + C * (ca * (ca - 1) / 2) + cr * ca + g;

  const int q0w = qtile * BM + wave * 16;

  // Q fragments (A-layout), fp32 global -> bf16 regs, once per block
  bf16x8_t qf[4];
  {
    const float* qrow = Q + (size_t)(q0w + l15) * DK + quad * 8;
    #pragma unroll
    for (int kb = 0; kb < 4; ++kb) {
      const float4* p = (const float4*)(qrow + kb * 32);
      float4 a = p[0], b = p[1];
      bf16x8_t f;
      f[0]=(__bf16)a.x; f[1]=(__bf16)a.y; f[2]=(__bf16)a.z; f[3]=(__bf16)a.w;
      f[4]=(__bf16)b.x; f[5]=(__bf16)b.y; f[6]=(__bf16)b.z; f[7]=(__bf16)b.w;
      qf[kb] = f;
    }
  }

  // per-thread staging sources (swizzled) + wave-uniform LDS offsets
  const __bf16* kp[4]; const __bf16* vp[4]; int loff[4];
  {
    const int ck = l15 ^ ((wave * 4 + quad) & 15);
    const int cv = (lane & 7) ^ ((lane >> 3) & 7);
    #pragma unroll
    for (int t = 0; t < 4; ++t) {
      const int rk = t * 16 + wave * 4 + quad;
      kp[t] = Kb + ((size_t)(jb0 * BN + rk)) * DK + ck * 8;
      const int rv = t * 32 + wave * 8 + (lane >> 3);
      vp[t] = Vtg + (size_t)rv * S_LEN + jb0 * BN + cv * 8;
      loff[t] = t * 2048 + wave * 512;
    }
  }

  floatx4 o_acc[8];
  #pragma unroll
  for (int dt = 0; dt < 8; ++dt) o_acc[dt] = (floatx4){0.f, 0.f, 0.f, 0.f};
  float m_r[4], l_r[4];
  #pragma unroll
  for (int r = 0; r < 4; ++r) { m_r[r] = -INFINITY; l_r[r] = 0.f; }

  // all-ones B-fragment: row-sum of P via MFMA (replaces shuffle-sum chain)
  bf16x8_t onesf;
  #pragma unroll
  for (int j = 0; j < 8; ++j) onesf[j] = (__bf16)1.0f;

  // prologue: stage K[jb0] into buf 0
  #pragma unroll
  for (int t = 0; t < 4; ++t) { GLD16(kp[t], &Ks[0][loff[t]]); kp[t] += BN * DK; }
  __syncthreads();

  int bsel = 0;
  for (int jb = jb0; jb < jb1; ++jb) {
    // prefetch next K tile into other buffer; stage current V tile.
    // Both latencies hide under QK + softmax below.
    if (jb + 1 < jb1) {
      #pragma unroll
      for (int t = 0; t < 4; ++t) { GLD16(kp[t], &Ks[bsel ^ 1][loff[t]]); kp[t] += BN * DK; }
    }
    #pragma unroll
    for (int t = 0; t < 4; ++t) { GLD16(vp[t], &Vts[loff[t]]); vp[t] += BN; }

    const __bf16* Kcur = Ks[bsel];

    // ---- S = Q K^T (swizzled B-frag reads) ----
    floatx4 sv[4];
    __builtin_amdgcn_s_setprio(1);
    #pragma unroll
    for (int n = 0; n < 4; ++n) {
      floatx4 acc = (floatx4){0.f, 0.f, 0.f, 0.f};
      #pragma unroll
      for (int kb = 0; kb < 4; ++kb) {
        bf16x8_t bfr = *(const bf16x8_t*)
            &Kcur[(n * 16 + l15) * DK + (((kb * 4 + quad) ^ l15) * 8)];
        acc = __builtin_amdgcn_mfma_f32_16x16x32_bf16(qf[kb], bfr, acc, 0, 0, 0);
      }
      sv[n] = acc;
    }
    __builtin_amdgcn_s_setprio(0);

    // ---- scale (log2 domain) + causal mask on diagonal tile only ----
    if (jb == qtile) {
      #pragma unroll
      for (int n = 0; n < 4; ++n) {
        const int key = jb * BN + n * 16 + l15;
        #pragma unroll
        for (int r = 0; r < 4; ++r) {
          const int qi = q0w + quad * 4 + r;
          const float vv = sv[n][r] * SCALE2;
          sv[n][r] = (key > qi) ? -1e30f : vv;
        }
      }
    } else {
      #pragma unroll
      for (int n = 0; n < 4; ++n)
        #pragma unroll
        for (int r = 0; r < 4; ++r) sv[n][r] *= SCALE2;
    }

    // ---- online softmax: row max ----
    float rm[4];
    #pragma unroll
    for (int r = 0; r < 4; ++r)
      rm[r] = fmaxf(fmaxf(sv[0][r], sv[1][r]), fmaxf(sv[2][r], sv[3][r]));
    #pragma unroll
    for (int off = 8; off >= 1; off >>= 1) {
      #pragma unroll
      for (int r = 0; r < 4; ++r) rm[r] = fmaxf(rm[r], __shfl_xor(rm[r], off));
    }

    // rescale only when some row's max actually grew (exact, not approximate)
    const int grow = (rm[0] > m_r[0]) || (rm[1] > m_r[1]) ||
                     (rm[2] > m_r[2]) || (rm[3] > m_r[3]);
    if (__any(grow)) {
      float al[4];
      #pragma unroll
      for (int r = 0; r < 4; ++r) {
        const float mn = fmaxf(m_r[r], rm[r]);
        al[r] = fexp2(m_r[r] - mn);
        m_r[r] = mn;
        l_r[r] *= al[r];
      }
      #pragma unroll
      for (int dt = 0; dt < 8; ++dt)
        #pragma unroll
        for (int r = 0; r < 4; ++r) o_acc[dt][r] *= al[r];
    }

    // ---- P = exp2(S - m): C-layout -> LDS (wave-private, no barrier needed) ----
    #pragma unroll
    for (int n = 0; n < 4; ++n)
      #pragma unroll
      for (int r = 0; r < 4; ++r)
        Pl[wave][quad * 4 + r][n * 16 + l15] = (__bf16)fexp2(sv[n][r] - m_r[r]);

    __syncthreads();   // V tile (and K prefetch) complete + visible to all waves

    // ---- O += P V; l += rowsum(P) via ones-MFMA ----
    floatx4 lacc = (floatx4){0.f, 0.f, 0.f, 0.f};
    __builtin_amdgcn_s_setprio(1);
    #pragma unroll
    for (int kc = 0; kc < 2; ++kc) {
      bf16x8_t af = *(const bf16x8_t*)&Pl[wave][l15][kc * 32 + quad * 8];
      lacc = __builtin_amdgcn_mfma_f32_16x16x32_bf16(af, onesf, lacc, 0, 0, 0);
      #pragma unroll
      for (int dt = 0; dt < 8; ++dt) {
        bf16x8_t vf = *(const bf16x8_t*)
            &Vts[(dt * 16 + l15) * BN + (((kc * 4 + quad) ^ (l15 & 7)) * 8)];
        o_acc[dt] = __builtin_amdgcn_mfma_f32_16x16x32_bf16(af, vf, o_acc[dt], 0, 0, 0);
      }
    }
    __builtin_amdgcn_s_setprio(0);
    #pragma unroll
    for (int r = 0; r < 4; ++r) l_r[r] += lacc[r];

    __syncthreads();   // all reads of Vts / Ks[bsel] done before next staging
    bsel ^= 1;
  }

  // ---- epilogue ----
  if (direct) {
    #pragma unroll
    for (int r = 0; r < 4; ++r) {
      const float inv = 1.0f / l_r[r];
      float* orow = Opart + (size_t)(q0w + quad * 4 + r) * DK + l15;
      #pragma unroll
      for (int dt = 0; dt < 8; ++dt) orow[dt * 16] = o_acc[dt][r] * inv;
    }
  } else {
    #pragma unroll
    for (int r = 0; r < 4; ++r) {
      const int row = wave * 16 + quad * 4 + r;
      float* orow = Opart + ((size_t)chunk * BM + row) * DK + l15;
      #pragma unroll
      for (int dt = 0; dt < 8; ++dt) orow[dt * 16] = o_acc[dt][r];
    }
    if (l15 == 0) {
      #pragma unroll
      for (int r = 0; r < 4; ++r) {
        const int row = wave * 16 + quad * 4 + r;
        stats[((size_t)chunk * BM + row) * 2 + 0] = m_r[r];   // log2 domain
        stats[((size_t)chunk * BM + row) * 2 + 1] = l_r[r];
      }
    }
  }
}

// ---- combine: wave per query row, lane covers a float2 column pair ----
__global__ __launch_bounds__(256)
void fa_reduce(const float* __restrict__ Opart, const float* __restrict__ stats,
               float* __restrict__ O, int C) {
  const int wave = threadIdx.x >> 6, lane = threadIdx.x & 63;
  const int row = blockIdx.x * 4 + wave;
  const int qt = row >> 6, r = row & 63;

  const int ca = qt / C, cr = qt - ca * C;
  const int base = qt + C * (ca * (ca - 1) / 2) + cr * ca;
  const int nch = ca + 1;

  float M = -INFINITY;
  for (int g = 0; g < nch; ++g)
    M = fmaxf(M, stats[((size_t)(base + g) * BM + r) * 2]);

  float L = 0.f, ax = 0.f, ay = 0.f;
  for (int g = 0; g < nch; ++g) {
    const size_t sidx = (size_t)(base + g) * BM + r;
    const float m = stats[sidx * 2];
    const float w = fexp2(m - M);
    L += stats[sidx * 2 + 1] * w;
    float2 o = *(const float2*)&Opart[sidx * DK + lane * 2];
    ax += w * o.x; ay += w * o.y;
  }
  const float inv = 1.f / L;
  float2 res; res.x = ax * inv; res.y = ay * inv;
  *(float2*)&O[(size_t)row * DK + lane * 2] = res;
}

extern "C" void kernel_launch(void* const* d_in, const int* in_sizes, int n_in,
                              void* d_out, int out_size, void* d_ws, size_t ws_size,
                              hipStream_t stream) {
  (void)in_sizes; (void)n_in; (void)out_size;
  const float* q = (const float*)d_in[0];
  const float* k = (const float*)d_in[1];
  const float* v = (const float*)d_in[2];
  float* out = (float*)d_out;

  const size_t conv_bytes = (size_t)S_LEN * DK * 2 * 2;        // Kb + Vt = 4 MB
  const size_t per_chunk  = (size_t)(BM * DK + 2 * BM) * 4;    // 33280 B

  // smallest fixed chunk size C (tiles of 64 keys) whose compact chunk set fits ws
  int C = 0; long long nc = 0;
  for (int c = 8; c <= NQT; ++c) {
    const int a = NQT / c, rr = NQT % c;
    const long long n = (long long)NQT + (long long)c * a * (a - 1) / 2 +
                        (long long)rr * a;
    if (conv_bytes + (size_t)n * per_chunk <= ws_size) { C = c; nc = n; break; }
  }

  __bf16* Kb = (__bf16*)d_ws;
  __bf16* Vt = Kb + (size_t)S_LEN * DK;

  prep_kv<<<(S_LEN * DK) / (256 * 4) + S_LEN / 64, 256, 0, stream>>>(k, v, Kb, Vt);

  if (C) {
    float* Opart = (float*)(Vt + (size_t)S_LEN * DK);
    float* stats = Opart + (size_t)nc * BM * DK;
    const int gy = (NQT - 1) / C + 1;
    fa_part<<<dim3(NQT, gy), 256, 0, stream>>>(q, Kb, Vt, Opart, stats, C, 0);
    fa_reduce<<<S_LEN / 4, 256, 0, stream>>>(Opart, stats, out, C);
  } else {
    fa_part<<<dim3(NQT, 1), 256, 0, stream>>>(q, Kb, Vt, out, out, NQT, 1);
  }
}

// Round 2
// 124.238 us; speedup vs baseline: 1.1029x; 1.0998x over previous
//
#include <hip/hip_runtime.h>
#include <hip/hip_bf16.h>
#include <math.h>

#define S_LEN 8192
#define DK    128
#define BM    128              // q rows per block (4 waves x 32)
#define BN    64               // keys per tile
#define NQT   (S_LEN / BM)     // 64 query tiles
// (1/sqrt(128)) * log2(e): softmax tracked in base-2 domain, folded into Q
#define SCALE2 (0.08838834764831845f * 1.4426950408889634f)

typedef __bf16 bf16x8_t __attribute__((ext_vector_type(8)));
typedef __bf16 bf16x4_t __attribute__((ext_vector_type(4)));
typedef __bf16 bf16x2_t __attribute__((ext_vector_type(2)));
typedef float  floatx16 __attribute__((ext_vector_type(16)));
typedef unsigned uintx4 __attribute__((ext_vector_type(4)));

// async global->LDS, 16 B per lane; LDS dst is wave-uniform base + lane*16
#define GLD16(g, l) __builtin_amdgcn_global_load_lds(                      \
    (const __attribute__((address_space(1))) void*)(g),                    \
    (__attribute__((address_space(3))) void*)(l), 16, 0, 0)

__device__ __forceinline__ float fexp2(float x) {
#if __has_builtin(__builtin_amdgcn_exp2f)
  return __builtin_amdgcn_exp2f(x);
#else
  return exp2f(x);
#endif
}

// pack two f32 -> one u32 of 2 bf16 (compiler emits cvt+pack; m240: don't hand-asm)
__device__ __forceinline__ unsigned pack2(float a, float b) {
  bf16x2_t w; w[0] = (__bf16)a; w[1] = (__bf16)b;
  return __builtin_bit_cast(unsigned, w);
}

// x' = [x_lo | y_lo], y' = [x_hi | y_hi]  (32-lane half exchange)
__device__ __forceinline__ void xswap(unsigned &x, unsigned &y) {
#if __has_builtin(__builtin_amdgcn_permlane32_swap)
  typedef unsigned v2u __attribute__((ext_vector_type(2)));
  v2u t = __builtin_amdgcn_permlane32_swap(x, y, false, false);
  x = t[0]; y = t[1];
#else
  const unsigned sx = (unsigned)__shfl_xor((int)x, 32);
  const unsigned sy = (unsigned)__shfl_xor((int)y, 32);
  const bool lo = ((threadIdx.x & 63) < 32);
  const unsigned nx = lo ? x : sy;
  const unsigned ny = lo ? sx : y;
  x = nx; y = ny;
#endif
}

// ---- fused prep: K fp32->bf16 row-major; V fp32->bf16 transposed Vt[d][s] ----
__global__ __launch_bounds__(256) void prep_kv(const float* __restrict__ K,
                                               const float* __restrict__ V,
                                               __bf16* __restrict__ Kb,
                                               __bf16* __restrict__ Vt) {
  __shared__ __bf16 t[64][DK + 8];
  const int bx  = blockIdx.x;
  const int tid = threadIdx.x;
  if (bx < (S_LEN * DK) / (256 * 4)) {            // K conversion part
    const int i = (bx * 256 + tid) * 4;
    float4 v = *(const float4*)&K[i];
    bf16x4_t b;
    b[0] = (__bf16)v.x; b[1] = (__bf16)v.y; b[2] = (__bf16)v.z; b[3] = (__bf16)v.w;
    *(bf16x4_t*)&Kb[i] = b;
    return;
  }
  // V transpose part
  const int key0 = (bx - (S_LEN * DK) / (256 * 4)) * 64;
  {
    const int r = tid >> 2, cg = (tid & 3) * 32;
    const float* vp = V + (size_t)(key0 + r) * DK + cg;
    #pragma unroll
    for (int i = 0; i < 8; ++i) {
      float4 v = ((const float4*)vp)[i];
      bf16x4_t b;
      b[0] = (__bf16)v.x; b[1] = (__bf16)v.y; b[2] = (__bf16)v.z; b[3] = (__bf16)v.w;
      *(bf16x4_t*)&t[r][cg + i * 4] = b;
    }
  }
  __syncthreads();
  const int d = tid >> 1, h = (tid & 1) * 32;
  __bf16* op = Vt + (size_t)d * S_LEN + key0 + h;
  #pragma unroll
  for (int jb = 0; jb < 4; ++jb) {
    bf16x8_t b;
    #pragma unroll
    for (int j = 0; j < 8; ++j) b[j] = t[h + jb * 8 + j][d];
    *(bf16x8_t*)&op[jb * 8] = b;
  }
}

// ---- flash attention partial: swapped-operand 32x32x16, in-register softmax ----
// Ks: [2][64 keys][128 d] bf16, XOR-swizzled 16B chunks: phys = c ^ (row&15)
// Vts: [2][128 d][64 keys] bf16, swizzled: phys = c ^ (row&7)
__global__ __launch_bounds__(256, 2)
void fa_part(const float* __restrict__ Q, const __bf16* __restrict__ Kb,
             const __bf16* __restrict__ Vtg, float* __restrict__ Opart,
             float* __restrict__ stats, int C, int direct) {
  __shared__ __align__(16) __bf16 Ks[2][BN * DK];   // 32 KB
  __shared__ __align__(16) __bf16 Vts[2][DK * BN];  // 32 KB

  const int tid  = threadIdx.x;
  const int wave = tid >> 6;
  const int lane = tid & 63;
  const int l31  = lane & 31;
  const int hh   = lane >> 5;

  const int qtile = (NQT - 1) - blockIdx.x;   // longest work first
  const int g     = blockIdx.y;
  const int nt    = 2 * qtile + 2;            // key tiles for this qtile
  const int jb0   = g * C;
  if (jb0 >= nt) return;
  const int jb1 = (jb0 + C < nt) ? (jb0 + C) : nt;
  // compact chunk index (C even, h2 = C/2): base(qt) = sum_{s<=qt} ceil(s/h2)
  const int h2 = C >> 1;
  const int ca = qtile / h2, cr = qtile - ca * h2;
  const int chunk = h2 * ca * (ca + 1) / 2 + cr * (ca + 1) + g;

  const int qw  = qtile * BM + wave * 32;     // wave's q base
  const int myq = qw + l31;                   // this lane's q row

  // Q fragments (B-layout of K*Q^T): lane holds Q[myq][s*16 + hh*8 + j], scaled
  bf16x8_t qf[8];
  {
    const float* qrow = Q + (size_t)myq * DK + hh * 8;
    #pragma unroll
    for (int s = 0; s < 8; ++s) {
      float4 x = *(const float4*)(qrow + s * 16);
      float4 y = *(const float4*)(qrow + s * 16 + 4);
      bf16x8_t f;
      f[0]=(__bf16)(x.x*SCALE2); f[1]=(__bf16)(x.y*SCALE2);
      f[2]=(__bf16)(x.z*SCALE2); f[3]=(__bf16)(x.w*SCALE2);
      f[4]=(__bf16)(y.x*SCALE2); f[5]=(__bf16)(y.y*SCALE2);
      f[6]=(__bf16)(y.z*SCALE2); f[7]=(__bf16)(y.w*SCALE2);
      qf[s] = f;
    }
  }

  // staging sources (pre-swizzled global) + wave-uniform LDS offsets
  const __bf16* kp[4]; const __bf16* vp[4]; int loff[4];
  {
    const int ck = (lane & 15) ^ ((wave * 4 + (lane >> 4)) & 15);
    const int cv = (lane & 7) ^ ((lane >> 3) & 7);
    #pragma unroll
    for (int t = 0; t < 4; ++t) {
      const int rk = t * 16 + wave * 4 + (lane >> 4);
      kp[t] = Kb + ((size_t)(jb0 * BN + rk)) * DK + ck * 8;
      const int rv = t * 32 + wave * 8 + (lane >> 3);
      vp[t] = Vtg + (size_t)rv * S_LEN + jb0 * BN + cv * 8;
      loff[t] = t * 2048 + wave * 512;
    }
  }

  floatx16 o_acc[4];
  #pragma unroll
  for (int d = 0; d < 4; ++d)
    #pragma unroll
    for (int r = 0; r < 16; ++r) o_acc[d][r] = 0.f;
  float m_r = -INFINITY, l_r = 0.f;

  // prologue: stage tile jb0 into buffer 0
  #pragma unroll
  for (int t = 0; t < 4; ++t) { GLD16(kp[t], &Ks[0][loff[t]]); kp[t] += BN * DK; }
  #pragma unroll
  for (int t = 0; t < 4; ++t) { GLD16(vp[t], &Vts[0][loff[t]]); vp[t] += BN; }
  __syncthreads();

  int cur = 0;
  for (int jb = jb0; jb < jb1; ++jb) {
    // stage NEXT tile into the other buffer. Safe: barrier just crossed
    // guarantees all waves finished reading buf cur^1 (tile jb-1). The
    // end-of-tile barrier drains these loads -> latency hidden under compute.
    if (jb + 1 < jb1) {
      #pragma unroll
      for (int t = 0; t < 4; ++t) { GLD16(kp[t], &Ks[cur ^ 1][loff[t]]); kp[t] += BN * DK; }
      #pragma unroll
      for (int t = 0; t < 4; ++t) { GLD16(vp[t], &Vts[cur ^ 1][loff[t]]); vp[t] += BN; }
    }

    // wave skips compute on fully-masked tiles (still stages + barriers)
    if (jb * 64 <= qw + 31) {
      const __bf16* Kc = Ks[cur];
      const __bf16* Vc = Vts[cur];

      // ---- S^T = K * Q^T : lane holds col q=myq, rows = 16 keys per half ----
      floatx16 sv[2];
      __builtin_amdgcn_s_setprio(1);
      #pragma unroll
      for (int g1 = 0; g1 < 2; ++g1) {
        floatx16 acc;
        #pragma unroll
        for (int r = 0; r < 16; ++r) acc[r] = 0.f;
        const int row = g1 * 32 + l31;
        #pragma unroll
        for (int s = 0; s < 8; ++s) {
          bf16x8_t kf = *(const bf16x8_t*)
              &Kc[row * DK + (((s * 2 + hh) ^ (row & 15)) * 8)];
          acc = __builtin_amdgcn_mfma_f32_32x32x16_bf16(kf, qf[s], acc, 0, 0, 0);
        }
        sv[g1] = acc;
      }
      __builtin_amdgcn_s_setprio(0);

      // ---- causal mask (diagonal region only; key/q both lane-local) ----
      if (jb * 64 + 63 > qw) {
        #pragma unroll
        for (int g1 = 0; g1 < 2; ++g1)
          #pragma unroll
          for (int r = 0; r < 16; ++r) {
            const int key = jb * 64 + g1 * 32 + (r & 3) + ((r >> 2) << 3) + (hh << 2);
            if (key > myq) sv[g1][r] = -1e30f;
          }
      }

      // ---- online softmax: all lane-local + one half-exchange ----
      float pm = sv[0][0];
      #pragma unroll
      for (int g1 = 0; g1 < 2; ++g1)
        #pragma unroll
        for (int r = 0; r < 16; ++r) pm = fmaxf(pm, sv[g1][r]);
      {
        unsigned b0 = __builtin_bit_cast(unsigned, pm), b1 = b0;
        xswap(b0, b1);
        pm = fmaxf(__builtin_bit_cast(float, b0), __builtin_bit_cast(float, b1));
      }
      const int grow = (pm > m_r) ? 1 : 0;
      if (__any(grow)) {
        const float mn = fmaxf(m_r, pm);
        const float al = fexp2(m_r - mn);
        m_r = mn; l_r *= al;
        #pragma unroll
        for (int d = 0; d < 4; ++d)
          #pragma unroll
          for (int r = 0; r < 16; ++r) o_acc[d][r] *= al;
      }

      float rs = 0.f;
      #pragma unroll
      for (int g1 = 0; g1 < 2; ++g1)
        #pragma unroll
        for (int r = 0; r < 16; ++r) {
          const float pv = fexp2(sv[g1][r] - m_r);
          sv[g1][r] = pv;
          rs += pv;
        }
      {
        unsigned b0 = __builtin_bit_cast(unsigned, rs), b1 = b0;
        xswap(b0, b1);
        l_r += __builtin_bit_cast(float, b0) + __builtin_bit_cast(float, b1);
      }

      // ---- P -> bf16 B-fragments in-register (pack + half swaps) ----
      unsigned pk[4][4];
      #pragma unroll
      for (int g1 = 0; g1 < 2; ++g1) {
        unsigned W0 = pack2(sv[g1][0],  sv[g1][1]);
        unsigned W1 = pack2(sv[g1][2],  sv[g1][3]);
        unsigned W2 = pack2(sv[g1][4],  sv[g1][5]);
        unsigned W3 = pack2(sv[g1][6],  sv[g1][7]);
        unsigned W4 = pack2(sv[g1][8],  sv[g1][9]);
        unsigned W5 = pack2(sv[g1][10], sv[g1][11]);
        unsigned W6 = pack2(sv[g1][12], sv[g1][13]);
        unsigned W7 = pack2(sv[g1][14], sv[g1][15]);
        xswap(W0, W2); xswap(W1, W3);   // -> keys 16g1+0..15
        xswap(W4, W6); xswap(W5, W7);   // -> keys 16g1+16..31 (of this 32-group)
        pk[g1*2+0][0]=W0; pk[g1*2+0][1]=W1; pk[g1*2+0][2]=W2; pk[g1*2+0][3]=W3;
        pk[g1*2+1][0]=W4; pk[g1*2+1][1]=W5; pk[g1*2+1][2]=W6; pk[g1*2+1][3]=W7;
      }

      // ---- O^T += V^T * P^T : lane holds col q=myq, rows = d ----
      __builtin_amdgcn_s_setprio(1);
      #pragma unroll
      for (int ks = 0; ks < 4; ++ks) {
        uintx4 u; u[0]=pk[ks][0]; u[1]=pk[ks][1]; u[2]=pk[ks][2]; u[3]=pk[ks][3];
        const bf16x8_t pf = __builtin_bit_cast(bf16x8_t, u);
        #pragma unroll
        for (int d = 0; d < 4; ++d) {
          const int row = d * 32 + l31;
          bf16x8_t vf = *(const bf16x8_t*)
              &Vc[row * BN + (((ks * 2 + hh) ^ (row & 7)) * 8)];
          o_acc[d] = __builtin_amdgcn_mfma_f32_32x32x16_bf16(vf, pf, o_acc[d], 0, 0, 0);
        }
      }
      __builtin_amdgcn_s_setprio(0);
    }

    __syncthreads();   // next-tile staging complete; cur buffers free to reuse
    cur ^= 1;
  }

  // ---- epilogue: O^T regs -> O[q][d] (lane owns row myq) ----
  if (direct) {
    const float inv = 1.0f / l_r;
    float* orow = Opart + (size_t)myq * DK;
    #pragma unroll
    for (int d = 0; d < 4; ++d)
      #pragma unroll
      for (int mI = 0; mI < 4; ++mI) {
        float4 st;
        st.x = o_acc[d][mI*4+0] * inv; st.y = o_acc[d][mI*4+1] * inv;
        st.z = o_acc[d][mI*4+2] * inv; st.w = o_acc[d][mI*4+3] * inv;
        *(float4*)&orow[d * 32 + mI * 8 + hh * 4] = st;
      }
  } else {
    float* orow = Opart + ((size_t)chunk * BM + wave * 32 + l31) * DK;
    #pragma unroll
    for (int d = 0; d < 4; ++d)
      #pragma unroll
      for (int mI = 0; mI < 4; ++mI) {
        float4 st;
        st.x = o_acc[d][mI*4+0]; st.y = o_acc[d][mI*4+1];
        st.z = o_acc[d][mI*4+2]; st.w = o_acc[d][mI*4+3];
        *(float4*)&orow[d * 32 + mI * 8 + hh * 4] = st;
      }
    if (hh == 0) {
      stats[((size_t)chunk * BM + wave * 32 + l31) * 2 + 0] = m_r;  // log2 domain
      stats[((size_t)chunk * BM + wave * 32 + l31) * 2 + 1] = l_r;
    }
  }
}

// ---- combine: wave per query row, lane covers a float2 column pair ----
__global__ __launch_bounds__(256)
void fa_reduce(const float* __restrict__ Opart, const float* __restrict__ stats,
               float* __restrict__ O, int C) {
  const int wave = threadIdx.x >> 6, lane = threadIdx.x & 63;
  const int row = blockIdx.x * 4 + wave;
  const int qt = row >> 7, r = row & 127;

  const int h2 = C >> 1;
  const int ca = qt / h2, cr = qt - ca * h2;
  const int base = h2 * ca * (ca + 1) / 2 + cr * (ca + 1);
  const int nch = (qt + h2) / h2;   // ceil((qt+1)/h2)

  float M = -INFINITY;
  for (int g = 0; g < nch; ++g)
    M = fmaxf(M, stats[((size_t)(base + g) * BM + r) * 2]);

  float L = 0.f, ax = 0.f, ay = 0.f;
  for (int g = 0; g < nch; ++g) {
    const size_t sidx = (size_t)(base + g) * BM + r;
    const float m = stats[sidx * 2];
    const float w = fexp2(m - M);
    L += stats[sidx * 2 + 1] * w;
    float2 o = *(const float2*)&Opart[sidx * DK + lane * 2];
    ax += w * o.x; ay += w * o.y;
  }
  const float inv = 1.f / L;
  float2 res; res.x = ax * inv; res.y = ay * inv;
  *(float2*)&O[(size_t)row * DK + lane * 2] = res;
}

extern "C" void kernel_launch(void* const* d_in, const int* in_sizes, int n_in,
                              void* d_out, int out_size, void* d_ws, size_t ws_size,
                              hipStream_t stream) {
  (void)in_sizes; (void)n_in; (void)out_size;
  const float* q = (const float*)d_in[0];
  const float* k = (const float*)d_in[1];
  const float* v = (const float*)d_in[2];
  float* out = (float*)d_out;

  const size_t conv_bytes = (size_t)S_LEN * DK * 2 * 2;        // Kb + Vt = 4 MB
  const size_t per_chunk  = (size_t)(BM * DK + 2 * BM) * 4;    // 66560 B

  // smallest even chunk size C (in 64-key tiles) whose compact chunk set fits
  int C = 0; long long nc = 0;
  for (int c = 8; c <= 2 * NQT; c += 2) {
    const int h2 = c / 2;
    const int a = NQT / h2, rr = NQT - a * h2;
    const long long n = (long long)h2 * a * (a + 1) / 2 + (long long)rr * (a + 1);
    if (conv_bytes + (size_t)n * per_chunk <= ws_size) { C = c; nc = n; break; }
  }

  __bf16* Kb = (__bf16*)d_ws;
  __bf16* Vt = Kb + (size_t)S_LEN * DK;

  prep_kv<<<(S_LEN * DK) / (256 * 4) + S_LEN / 64, 256, 0, stream>>>(k, v, Kb, Vt);

  if (C) {
    float* Opart = (float*)(Vt + (size_t)S_LEN * DK);
    float* stats = Opart + (size_t)nc * BM * DK;
    const int gy = (2 * NQT + C - 1) / C;
    fa_part<<<dim3(NQT, gy), 256, 0, stream>>>(q, Kb, Vt, Opart, stats, C, 0);
    fa_reduce<<<S_LEN / 4, 256, 0, stream>>>(Opart, stats, out, C);
  } else {
    fa_part<<<dim3(NQT, 1), 256, 0, stream>>>(q, Kb, Vt, out, out, 2 * NQT, 1);
  }
}